// Round 1
// 902.214 us; speedup vs baseline: 1.1235x; 1.1235x over previous
//
#include <hip/hip_runtime.h>
#include <hip/hip_bf16.h>
#include <math.h>

using bf16 = __hip_bfloat16;
typedef __attribute__((ext_vector_type(4))) float f32x4;
typedef __attribute__((ext_vector_type(8))) short s16x8;

#define BM 128
#define BN 128
#define BK 32

__device__ __forceinline__ short f2b(float f) {
  bf16 h = __float2bfloat16(f);
  short s; __builtin_memcpy(&s, &h, 2); return s;
}

// async global->LDS, 16B per lane. LDS dest must be linear in lane order
// (wave-uniform base + lane*16) -- our tid*16B staging layout satisfies this.
__device__ __forceinline__ void async16(const bf16* g, bf16* l) {
  __builtin_amdgcn_global_load_lds(
      (const __attribute__((address_space(1))) void*)g,
      (__attribute__((address_space(3))) void*)l, 16, 0, 0);
}

// NT GEMM, all-bf16 inputs, global_load_lds staging (m97 structure).
// C[m][n] = alpha * sum_k A[m][k]*B[n][k]
// MODE 0: projection scatter into (H*B,S,hd): row=s*16+b, col=h*512+e
// MODE 1: scores, z in [0,64): A,B += z*262144; C += (z&15)*1048576+(z>>4)*512, ldc=2048
// MODE 2: PV: A += (z&15)*1048576+(z>>4)*512 (lda 2048); B += z*262144; C += ((z&15)*4+(z>>4))*262144
// MODE 3: plain row-major
template<int MODE, bool CF32>
__global__ __launch_bounds__(256) void gemm_nt(const bf16* __restrict__ Ain,
    const bf16* __restrict__ Bin, void* __restrict__ Cout,
    int K, int lda, int ldb, int ldc, float alpha)
{
  __shared__ bf16 sA[BM * BK];
  __shared__ bf16 sB[BN * BK];

  const int tid  = threadIdx.x;
  const int lane = tid & 63;
  const int wave = tid >> 6;
  const int quad = lane >> 4;
  const int l16  = lane & 15;

  size_t aBase = 0, bBase = 0, cBase = 0;
  if (MODE == 1) {
    const int z = blockIdx.z;
    aBase = (size_t)z * 262144;
    bBase = (size_t)z * 262144;
    cBase = (size_t)(z & 15) * 1048576 + (size_t)(z >> 4) * 512;
  } else if (MODE == 2) {
    const int z = blockIdx.z;
    aBase = (size_t)(z & 15) * 1048576 + (size_t)(z >> 4) * 512;
    bBase = (size_t)z * 262144;
    cBase = (size_t)((z & 15) * 4 + (z >> 4)) * 262144;
  }

  const int tileM = blockIdx.y * BM;
  const int tileN = blockIdx.x * BN;

  // staging: thread t covers 8 elems at row (t>>2), col ((t&3)*8); two 64-row halves.
  // LDS byte offset = tid*16 (half 0) / 4096+tid*16 (half 1): linear in lane. 
  const int sRow = tid >> 2;
  const int sCol = (tid & 3) * 8;
  const bf16* aSrc = Ain + aBase + (size_t)(tileM + sRow) * lda + sCol;
  const bf16* bSrc = Bin + bBase + (size_t)(tileN + sRow) * ldb + sCol;
  const size_t aStep = (size_t)64 * lda;
  const size_t bStep = (size_t)64 * ldb;
  bf16* aDst = sA + sRow * BK + sCol;
  bf16* bDst = sB + sRow * BK + sCol;

  const int warpRow = (wave >> 1) * 64;
  const int warpCol = (wave & 1) * 64;

  f32x4 acc[4][4] = {};

  for (int k0 = 0; k0 < K; k0 += BK) {
    __syncthreads();  // prior iteration's LDS reads complete before DMA overwrite
    async16(aSrc + k0,         aDst);
    async16(aSrc + k0 + aStep, aDst + 64 * BK);
    async16(bSrc + k0,         bDst);
    async16(bSrc + k0 + bStep, bDst + 64 * BK);
    __syncthreads();  // compiler drains vmcnt(0) before s_barrier -> LDS populated

    s16x8 af[4], bfr[4];
#pragma unroll
    for (int mi = 0; mi < 4; mi++)
      af[mi] = *(const s16x8*)(sA + (warpRow + mi * 16 + l16) * BK + quad * 8);
#pragma unroll
    for (int ni = 0; ni < 4; ni++)
      bfr[ni] = *(const s16x8*)(sB + (warpCol + ni * 16 + l16) * BK + quad * 8);
#pragma unroll
    for (int mi = 0; mi < 4; mi++)
#pragma unroll
      for (int ni = 0; ni < 4; ni++)
        acc[mi][ni] = __builtin_amdgcn_mfma_f32_16x16x32_bf16(af[mi], bfr[ni], acc[mi][ni], 0, 0, 0);
  }

  // epilogue: C/D layout col=lane&15, row=(lane>>4)*4+reg (verified m89/m91)
#pragma unroll
  for (int mi = 0; mi < 4; mi++) {
#pragma unroll
    for (int ni = 0; ni < 4; ni++) {
      f32x4 v = acc[mi][ni];
      const int col = tileN + warpCol + ni * 16 + l16;
#pragma unroll
      for (int r = 0; r < 4; r++) {
        const int row = tileM + warpRow + mi * 16 + quad * 4 + r;
        const float val = v[r] * alpha;
        size_t dst;
        if (MODE == 0) {
          // dest[(h*16+b)][s][e]: h=col>>9, b=row&15, s=row>>4, e=col&511
          dst = (((size_t)((col >> 9) * 16 + (row & 15)) * 512 + (size_t)(row >> 4)) * 512)
                + (size_t)(col & 511);
        } else {
          dst = cBase + (size_t)row * ldc + (size_t)col;
        }
        if (CF32) ((float*)Cout)[dst] = val;
        else      ((bf16*)Cout)[dst] = __float2bfloat16(val);
      }
    }
  }
}

// batched fp32 -> bf16 conversion, up to 6 tensors selected by blockIdx.y
struct Conv6 {
  const float* src[6];
  bf16* dst[6];
  int n[6];
};

__global__ __launch_bounds__(256) void convert6(Conv6 a) {
  const int t = blockIdx.y;
  const float* __restrict__ src = a.src[t];
  bf16* __restrict__ dst = a.dst[t];
  const size_t n = (size_t)a.n[t];
  const size_t stride = (size_t)gridDim.x * 2048;  // 256 threads * 8 elems
  for (size_t i = ((size_t)blockIdx.x * 256 + threadIdx.x) * 8; i < n; i += stride) {
    f32x4 x = *(const f32x4*)(src + i);
    f32x4 y = *(const f32x4*)(src + i + 4);
    s16x8 r;
    r[0] = f2b(x[0]); r[1] = f2b(x[1]); r[2] = f2b(x[2]); r[3] = f2b(x[3]);
    r[4] = f2b(y[0]); r[5] = f2b(y[1]); r[6] = f2b(y[2]); r[7] = f2b(y[3]);
    *(s16x8*)(dst + i) = r;
  }
}

// in-place fp32 softmax over 32768 contiguous rows of 512; one wave per row.
// Also emits bf16 copy (same flat layout) for the PV GEMM's A operand.
__global__ __launch_bounds__(256) void softmax512f(float* __restrict__ P,
                                                   bf16* __restrict__ Pb) {
  const int row  = blockIdx.x * 4 + (threadIdx.x >> 6);
  const int lane = threadIdx.x & 63;
  float* p = P + (size_t)row * 512 + lane * 8;
  bf16* pb = Pb + (size_t)row * 512 + lane * 8;

  f32x4 a = *(const f32x4*)p;
  f32x4 b = *(const f32x4*)(p + 4);
  float v[8];
  float m = -1e30f;
#pragma unroll
  for (int j = 0; j < 4; j++) { v[j] = a[j]; v[j + 4] = b[j]; }
#pragma unroll
  for (int j = 0; j < 8; j++) m = fmaxf(m, v[j]);
#pragma unroll
  for (int off = 32; off > 0; off >>= 1) m = fmaxf(m, __shfl_xor(m, off, 64));
  float s = 0.f;
#pragma unroll
  for (int j = 0; j < 8; j++) { v[j] = __expf(v[j] - m); s += v[j]; }
#pragma unroll
  for (int off = 32; off > 0; off >>= 1) s += __shfl_xor(s, off, 64);
  const float inv = 1.f / s;
  f32x4 oa, ob;
  s16x8 rb;
#pragma unroll
  for (int j = 0; j < 4; j++) { oa[j] = v[j] * inv; ob[j] = v[j + 4] * inv; }
#pragma unroll
  for (int j = 0; j < 8; j++) rb[j] = f2b(v[j] * inv);
  *(f32x4*)p = oa;
  *(f32x4*)(p + 4) = ob;
  *(s16x8*)pb = rb;
}

// batched 512x512 bf16 transpose: VT[n][e][t] = V[n][t][e]
__global__ __launch_bounds__(256) void transpose512(const bf16* __restrict__ V,
                                                    bf16* __restrict__ VT) {
  __shared__ bf16 tile[32][33];
  const int n = blockIdx.z;
  const bf16* src = V + (size_t)n * 262144;
  bf16* dst = VT + (size_t)n * 262144;
  const int x = blockIdx.x * 32 + threadIdx.x;
#pragma unroll
  for (int i = 0; i < 32; i += 8)
    tile[threadIdx.y + i][threadIdx.x] =
        src[(size_t)(blockIdx.y * 32 + threadIdx.y + i) * 512 + x];
  __syncthreads();
  const int tcol = blockIdx.y * 32 + threadIdx.x;
#pragma unroll
  for (int i = 0; i < 32; i += 8)
    dst[(size_t)(blockIdx.x * 32 + threadIdx.y + i) * 512 + tcol] =
        tile[threadIdx.x][threadIdx.y + i];
}

extern "C" void kernel_launch(void* const* d_in, const int* in_sizes, int n_in,
                              void* d_out, int out_size, void* d_ws, size_t ws_size,
                              hipStream_t stream) {
  const float* query = (const float*)d_in[0];  // fp32 (512,16,2048)
  const float* key   = (const float*)d_in[1];
  const float* value = (const float*)d_in[2];
  const float* Wq = (const float*)d_in[3];     // fp32 (2048,2048)
  const float* Wk = (const float*)d_in[4];
  const float* Wv = (const float*)d_in[5];
  const float* Wo = (const float*)d_in[6];
  float* out = (float*)d_out;             // output (S,B,D) fp32, 16777216 elems
  float* P   = out + 16777216;            // attn_score (B,S,H,t) fp32, rows of 512

  // scratch slots (each 16777216 bf16 = 32 MiB):
  //   ws0/ws1: workspace halves; o0/o1: dead halves of out[] until final GEMM;
  //   p0/p1: P region, free until scores GEMM writes it.
  bf16* ws0 = (bf16*)d_ws;
  bf16* ws1 = ws0 + 16777216;
  bf16* o0  = (bf16*)d_out;
  bf16* o1  = o0 + 16777216;
  bf16* p0  = (bf16*)P;
  bf16* p1  = p0 + 16777216;

  const dim3 blk(256);
  const float inv_sqrt_hd = 0.04419417382415922f;  // 1/sqrt(512)

  // 1. batch-convert q,k,v + Wq,Wk,Wv to bf16 (Wo converted later; its slot
  //    in p1 would be clobbered by the scores GEMM).
  Conv6 c;
  c.src[0] = query; c.dst[0] = ws0;           c.n[0] = 16777216;  // qb
  c.src[1] = key;   c.dst[1] = ws1;           c.n[1] = 16777216;  // kb
  c.src[2] = value; c.dst[2] = p0;            c.n[2] = 16777216;  // vb
  c.src[3] = Wq;    c.dst[3] = p1;            c.n[3] = 4194304;   // Wqb
  c.src[4] = Wk;    c.dst[4] = p1 + 4194304;  c.n[4] = 4194304;   // Wkb
  c.src[5] = Wv;    c.dst[5] = p1 + 8388608;  c.n[5] = 4194304;   // Wvb
  convert6<<<dim3(2048, 6), blk, 0, stream>>>(c);

  // 2. projections: (8192x2048) @ W^T, scatter to (H*B,S,hd) bf16
  gemm_nt<0, false><<<dim3(16, 64, 1), blk, 0, stream>>>(ws0, p1,           o0,  2048, 2048, 2048, 0, 1.0f);  // Q
  gemm_nt<0, false><<<dim3(16, 64, 1), blk, 0, stream>>>(ws1, p1 + 4194304, o1,  2048, 2048, 2048, 0, 1.0f);  // K
  gemm_nt<0, false><<<dim3(16, 64, 1), blk, 0, stream>>>(p0,  p1 + 8388608, ws0, 2048, 2048, 2048, 0, 1.0f);  // V

  // 3. V(ws0) -> VT(ws1); kb in ws1 is dead after K projection
  transpose512<<<dim3(16, 16, 64), dim3(32, 8), 0, stream>>>(ws0, ws1);

  // 4. scores: per-head 512^3, fp32 epilogue straight into P (final attn layout);
  //    overwrites p0/p1 scratch (vb + weights, all dead)
  gemm_nt<1, true><<<dim3(4, 4, 64), blk, 0, stream>>>(o0, o1, P, 512, 512, 512, 2048, inv_sqrt_hd);

  // 5. softmax in place on fp32 P; bf16 copy Pb -> o0 (Q dead)
  softmax512f<<<dim3(8192), blk, 0, stream>>>(P, o0);

  // 6. PV: A = Pb (o0), B = VT (ws1) -> X bf16 (B,H,S,hd) flat @ ws0 (V dead)
  gemm_nt<2, false><<<dim3(4, 4, 64), blk, 0, stream>>>(o0, ws1, ws0, 512, 2048, 512, 512, 1.0f);

  // 7. convert Wo -> ws1 (VT dead after PV)
  Conv6 cw;
  for (int i = 0; i < 6; i++) { cw.src[i] = Wo; cw.dst[i] = ws1; cw.n[i] = 4194304; }
  convert6<<<dim3(2048, 1), blk, 0, stream>>>(cw);

  // 8. final: out = X @ Wo^T, fp32 row-major (S,B,D). Reads only ws (X, Wob);
  //    writes o0/o1 region (Pb dead) -- no overlap race.
  gemm_nt<3, true><<<dim3(16, 64, 1), blk, 0, stream>>>(ws0, ws1, out, 2048, 2048, 2048, 2048, 1.0f);
}

// Round 2
// 698.144 us; speedup vs baseline: 1.4519x; 1.2923x over previous
//
#include <hip/hip_runtime.h>
#include <hip/hip_bf16.h>
#include <math.h>

using bf16 = __hip_bfloat16;
typedef __attribute__((ext_vector_type(4))) float f32x4;
typedef __attribute__((ext_vector_type(8))) short s16x8;

#define BM 256
#define BN 256
#define BK 32
// LDS ring: 4 slots x (A 256x32 + B 256x32) bf16 = 4 x 32KiB = 128 KiB
#define SLOT 16384  // bf16 elements per slot
#define BREG 8192   // bf16 offset of B region within slot

__device__ __forceinline__ short f2b(float f) {
  bf16 h = __float2bfloat16(f);
  short s; __builtin_memcpy(&s, &h, 2); return s;
}

// async global->LDS, 16B per lane. LDS dest is linear in lane order.
__device__ __forceinline__ void async16(const bf16* g, bf16* l) {
  __builtin_amdgcn_global_load_lds(
      (const __attribute__((address_space(1))) void*)g,
      (__attribute__((address_space(3))) void*)l, 16, 0, 0);
}

// NT GEMM, bf16 inputs, 256x256 tile, BK=32, 8 waves (2M x 4N), 4-deep LDS ring,
// counted-vmcnt pipeline (lead ~2 windows), source-swizzled LDS (bank-conflict-free),
// setprio around MFMA cluster. Grid is always 256 blocks = 1/CU.
// C[m][n] = alpha * sum_k A[m][k]*B[n][k]
// MODE 0: projection scatter into (H*B,S,hd): row=s*16+b, col=h*512+e
// MODE 1: scores, z in [0,64): A,B += z*262144; C += (z&15)*1048576+(z>>4)*512, ldc=2048
// MODE 2: PV: A += (z&15)*1048576+(z>>4)*512 (lda 2048); B += z*262144; C += ((z&15)*4+(z>>4))*262144
// MODE 3: plain row-major
template<int MODE, bool CF32>
__global__ __launch_bounds__(512, 2) void gemm_nt(const bf16* __restrict__ Ain,
    const bf16* __restrict__ Bin, void* __restrict__ Cout,
    int K, int lda, int ldb, int ldc, float alpha)
{
  __shared__ bf16 lds[4 * SLOT];  // 131072 B

  const int tid  = threadIdx.x;
  const int lane = tid & 63;
  const int wave = tid >> 6;
  const int quad = lane >> 4;
  const int l16  = lane & 15;

  // bijective XCD swizzle over the linear block id (nwg = 256, %8 == 0)
  const int nwg = gridDim.x * gridDim.y * gridDim.z;
  int bid = (blockIdx.z * gridDim.y + blockIdx.y) * gridDim.x + blockIdx.x;
  bid = (bid & 7) * (nwg >> 3) + (bid >> 3);
  const int bx = bid % gridDim.x;
  int rest = bid / gridDim.x;
  const int by = rest % gridDim.y;
  const int bz = rest / gridDim.y;

  size_t aBase = 0, bBase = 0, cBase = 0;
  if (MODE == 1) {
    aBase = (size_t)bz * 262144;
    bBase = (size_t)bz * 262144;
    cBase = (size_t)(bz & 15) * 1048576 + (size_t)(bz >> 4) * 512;
  } else if (MODE == 2) {
    aBase = (size_t)(bz & 15) * 1048576 + (size_t)(bz >> 4) * 512;
    bBase = (size_t)bz * 262144;
    cBase = (size_t)((bz & 15) * 4 + (bz >> 4)) * 262144;
  }

  const int tileM = by * BM;
  const int tileN = bx * BN;

  // ---- staging addresses ----
  // thread t stages 16B at LDS bf16-off t*8 within each 4096-elem half-region.
  // LDS is linear; the SOURCE col-block is pre-swizzled: q = (t&3) ^ ((t>>3)&3).
  // Matching read swizzle: slot = quad ^ ((row>>1)&3).  (2-way bank aliasing = free)
  const int sRow = tid >> 2;                     // 0..127
  const int sQ   = (tid & 3) ^ ((tid >> 3) & 3);
  const int sCol = sQ * 8;
  const size_t aOff0 = aBase + (size_t)(tileM + sRow) * lda + sCol;
  const size_t aOff1 = aOff0 + (size_t)128 * lda;
  const size_t bOff0 = bBase + (size_t)(tileN + sRow) * ldb + sCol;
  const size_t bOff1 = bOff0 + (size_t)128 * ldb;
  const int t8 = tid * 8;

  // ---- fragment read offsets (bf16 units, excluding ring-slot term) ----
  const int warpRow = (wave >> 2) * 128;   // 2 waves along M
  const int warpCol = (wave & 3) * 64;     // 4 waves along N
  int offA[8], offB[4];
#pragma unroll
  for (int mi = 0; mi < 8; mi++) {
    const int R = warpRow + mi * 16 + l16;
    offA[mi] = R * 32 + ((quad ^ ((R >> 1) & 3)) * 8);
  }
#pragma unroll
  for (int ni = 0; ni < 4; ni++) {
    const int R = warpCol + ni * 16 + l16;
    offB[ni] = BREG + R * 32 + ((quad ^ ((R >> 1) & 3)) * 8);
  }

  f32x4 acc[8][4] = {};
  const int NT = K / BK;

  // ---- prologue: stage tiles 0,1,2 into slots 0,1,2 ----
#pragma unroll
  for (int p = 0; p < 3; ++p) {
    bf16* base = lds + p * SLOT;
    const int ks = p * BK;
    async16(Ain + aOff0 + ks, base + t8);
    async16(Ain + aOff1 + ks, base + 4096 + t8);
    async16(Bin + bOff0 + ks, base + BREG + t8);
    async16(Bin + bOff1 + ks, base + BREG + 4096 + t8);
  }
  // 12 loads out; wait to 8 -> tile 0 (oldest 4) resident
  asm volatile("s_waitcnt vmcnt(8)" ::: "memory");
  __builtin_amdgcn_s_barrier();

  // ---- main loop: one window per K-tile ----
  for (int g = 0; g < NT; ++g) {
    // issue DMA for tile g+3 into slot (g+3)&3 (its previous contents' reads
    // finished before the barrier ending window g-1 -> no WAR race)
    if (g + 3 < NT) {
      bf16* base = lds + ((g + 3) & 3) * SLOT;
      const int ks = (g + 3) * BK;
      async16(Ain + aOff0 + ks, base + t8);
      async16(Ain + aOff1 + ks, base + 4096 + t8);
      async16(Bin + bOff0 + ks, base + BREG + t8);
      async16(Bin + bOff1 + ks, base + BREG + 4096 + t8);
    }

    const bf16* lb = lds + (g & 3) * SLOT;
    s16x8 af[8], bfr[4];
#pragma unroll
    for (int mi = 0; mi < 8; mi++) af[mi] = *(const s16x8*)(lb + offA[mi]);
#pragma unroll
    for (int ni = 0; ni < 4; ni++) bfr[ni] = *(const s16x8*)(lb + offB[ni]);

    __builtin_amdgcn_s_setprio(1);
#pragma unroll
    for (int mi = 0; mi < 8; mi++)
#pragma unroll
      for (int ni = 0; ni < 4; ni++)
        acc[mi][ni] = __builtin_amdgcn_mfma_f32_16x16x32_bf16(af[mi], bfr[ni], acc[mi][ni], 0, 0, 0);
    __builtin_amdgcn_s_setprio(0);

    // counted drain: after the barrier, loads except the newest N are complete
    // for ALL waves -> tile g+1 resident for window g+1. Never drains in-flight
    // prefetch depth in steady state; tail drains 8 -> 4 -> 0.
    if (g < NT - 1) {
      const int ahead = (g + 3 < NT ? 2 : (g + 2 < NT ? NT - 2 - g : 0));
      if (ahead == 2)      asm volatile("s_waitcnt vmcnt(8)" ::: "memory");
      else if (ahead == 1) asm volatile("s_waitcnt vmcnt(4)" ::: "memory");
      else                 asm volatile("s_waitcnt vmcnt(0)" ::: "memory");
      __builtin_amdgcn_s_barrier();
    }
  }

  // ---- epilogue: C/D layout col=lane&15, row=(lane>>4)*4+reg ----
#pragma unroll
  for (int mi = 0; mi < 8; mi++) {
#pragma unroll
    for (int ni = 0; ni < 4; ni++) {
      f32x4 v = acc[mi][ni];
      const int col = tileN + warpCol + ni * 16 + l16;
#pragma unroll
      for (int r = 0; r < 4; r++) {
        const int row = tileM + warpRow + mi * 16 + quad * 4 + r;
        const float val = v[r] * alpha;
        size_t dst;
        if (MODE == 0) {
          // dest[(h*16+b)][s][e]: h=col>>9, b=row&15, s=row>>4, e=col&511
          dst = (((size_t)((col >> 9) * 16 + (row & 15)) * 512 + (size_t)(row >> 4)) * 512)
                + (size_t)(col & 511);
        } else {
          dst = cBase + (size_t)row * ldc + (size_t)col;
        }
        if (CF32) ((float*)Cout)[dst] = val;
        else      ((bf16*)Cout)[dst] = __float2bfloat16(val);
      }
    }
  }
}

// batched fp32 -> bf16 conversion, up to 6 tensors selected by blockIdx.y
struct Conv6 {
  const float* src[6];
  bf16* dst[6];
  int n[6];
};

__global__ __launch_bounds__(256) void convert6(Conv6 a) {
  const int t = blockIdx.y;
  const float* __restrict__ src = a.src[t];
  bf16* __restrict__ dst = a.dst[t];
  const size_t n = (size_t)a.n[t];
  const size_t stride = (size_t)gridDim.x * 2048;  // 256 threads * 8 elems
  for (size_t i = ((size_t)blockIdx.x * 256 + threadIdx.x) * 8; i < n; i += stride) {
    f32x4 x = *(const f32x4*)(src + i);
    f32x4 y = *(const f32x4*)(src + i + 4);
    s16x8 r;
    r[0] = f2b(x[0]); r[1] = f2b(x[1]); r[2] = f2b(x[2]); r[3] = f2b(x[3]);
    r[4] = f2b(y[0]); r[5] = f2b(y[1]); r[6] = f2b(y[2]); r[7] = f2b(y[3]);
    *(s16x8*)(dst + i) = r;
  }
}

// in-place fp32 softmax over 32768 contiguous rows of 512; one wave per row.
// Also emits bf16 copy (same flat layout) for the PV GEMM's A operand.
__global__ __launch_bounds__(256) void softmax512f(float* __restrict__ P,
                                                   bf16* __restrict__ Pb) {
  const int row  = blockIdx.x * 4 + (threadIdx.x >> 6);
  const int lane = threadIdx.x & 63;
  float* p = P + (size_t)row * 512 + lane * 8;
  bf16* pb = Pb + (size_t)row * 512 + lane * 8;

  f32x4 a = *(const f32x4*)p;
  f32x4 b = *(const f32x4*)(p + 4);
  float v[8];
  float m = -1e30f;
#pragma unroll
  for (int j = 0; j < 4; j++) { v[j] = a[j]; v[j + 4] = b[j]; }
#pragma unroll
  for (int j = 0; j < 8; j++) m = fmaxf(m, v[j]);
#pragma unroll
  for (int off = 32; off > 0; off >>= 1) m = fmaxf(m, __shfl_xor(m, off, 64));
  float s = 0.f;
#pragma unroll
  for (int j = 0; j < 8; j++) { v[j] = __expf(v[j] - m); s += v[j]; }
#pragma unroll
  for (int off = 32; off > 0; off >>= 1) s += __shfl_xor(s, off, 64);
  const float inv = 1.f / s;
  f32x4 oa, ob;
  s16x8 rb;
#pragma unroll
  for (int j = 0; j < 4; j++) { oa[j] = v[j] * inv; ob[j] = v[j + 4] * inv; }
#pragma unroll
  for (int j = 0; j < 8; j++) rb[j] = f2b(v[j] * inv);
  *(f32x4*)p = oa;
  *(f32x4*)(p + 4) = ob;
  *(s16x8*)pb = rb;
}

// batched 512x512 bf16 transpose: VT[n][e][t] = V[n][t][e]
__global__ __launch_bounds__(256) void transpose512(const bf16* __restrict__ V,
                                                    bf16* __restrict__ VT) {
  __shared__ bf16 tile[32][33];
  const int n = blockIdx.z;
  const bf16* src = V + (size_t)n * 262144;
  bf16* dst = VT + (size_t)n * 262144;
  const int x = blockIdx.x * 32 + threadIdx.x;
#pragma unroll
  for (int i = 0; i < 32; i += 8)
    tile[threadIdx.y + i][threadIdx.x] =
        src[(size_t)(blockIdx.y * 32 + threadIdx.y + i) * 512 + x];
  __syncthreads();
  const int tcol = blockIdx.y * 32 + threadIdx.x;
#pragma unroll
  for (int i = 0; i < 32; i += 8)
    dst[(size_t)(blockIdx.x * 32 + threadIdx.y + i) * 512 + tcol] =
        tile[threadIdx.x][threadIdx.y + i];
}

extern "C" void kernel_launch(void* const* d_in, const int* in_sizes, int n_in,
                              void* d_out, int out_size, void* d_ws, size_t ws_size,
                              hipStream_t stream) {
  const float* query = (const float*)d_in[0];  // fp32 (512,16,2048)
  const float* key   = (const float*)d_in[1];
  const float* value = (const float*)d_in[2];
  const float* Wq = (const float*)d_in[3];     // fp32 (2048,2048)
  const float* Wk = (const float*)d_in[4];
  const float* Wv = (const float*)d_in[5];
  const float* Wo = (const float*)d_in[6];
  float* out = (float*)d_out;             // output (S,B,D) fp32, 16777216 elems
  float* P   = out + 16777216;            // attn_score (B,S,H,t) fp32, rows of 512

  // scratch slots (each 16777216 bf16 = 32 MiB)
  bf16* ws0 = (bf16*)d_ws;
  bf16* ws1 = ws0 + 16777216;
  bf16* o0  = (bf16*)d_out;
  bf16* o1  = o0 + 16777216;
  bf16* p0  = (bf16*)P;
  bf16* p1  = p0 + 16777216;

  const dim3 blk(256);
  const dim3 gblk(512);
  const float inv_sqrt_hd = 0.04419417382415922f;  // 1/sqrt(512)

  // 1. batch-convert q,k,v + Wq,Wk,Wv to bf16 (Wo later: its slot in p1 is
  //    clobbered by the scores GEMM).
  Conv6 c;
  c.src[0] = query; c.dst[0] = ws0;           c.n[0] = 16777216;  // qb
  c.src[1] = key;   c.dst[1] = ws1;           c.n[1] = 16777216;  // kb
  c.src[2] = value; c.dst[2] = p0;            c.n[2] = 16777216;  // vb
  c.src[3] = Wq;    c.dst[3] = p1;            c.n[3] = 4194304;   // Wqb
  c.src[4] = Wk;    c.dst[4] = p1 + 4194304;  c.n[4] = 4194304;   // Wkb
  c.src[5] = Wv;    c.dst[5] = p1 + 8388608;  c.n[5] = 4194304;   // Wvb
  convert6<<<dim3(2048, 6), blk, 0, stream>>>(c);

  // 2. projections: (8192x2048) @ W^T, scatter to (H*B,S,hd) bf16
  gemm_nt<0, false><<<dim3(8, 32, 1), gblk, 0, stream>>>(ws0, p1,           o0,  2048, 2048, 2048, 0, 1.0f);  // Q
  gemm_nt<0, false><<<dim3(8, 32, 1), gblk, 0, stream>>>(ws1, p1 + 4194304, o1,  2048, 2048, 2048, 0, 1.0f);  // K
  gemm_nt<0, false><<<dim3(8, 32, 1), gblk, 0, stream>>>(p0,  p1 + 8388608, ws0, 2048, 2048, 2048, 0, 1.0f);  // V

  // 3. V(ws0) -> VT(ws1); kb in ws1 is dead after K projection
  transpose512<<<dim3(16, 16, 64), dim3(32, 8), 0, stream>>>(ws0, ws1);

  // 4. scores: per-head 512^3, fp32 epilogue straight into P (final attn layout)
  gemm_nt<1, true><<<dim3(2, 2, 64), gblk, 0, stream>>>(o0, o1, P, 512, 512, 512, 2048, inv_sqrt_hd);

  // 5. softmax in place on fp32 P; bf16 copy Pb -> o0 (Q dead)
  softmax512f<<<dim3(8192), blk, 0, stream>>>(P, o0);

  // 6. PV: A = Pb (o0, 2048-stride view), B = VT (ws1) -> X bf16 (B,H,S,hd) @ ws0
  gemm_nt<2, false><<<dim3(2, 2, 64), gblk, 0, stream>>>(o0, ws1, ws0, 512, 2048, 512, 512, 1.0f);

  // 7. convert Wo -> ws1 (VT dead after PV)
  Conv6 cw;
  for (int i = 0; i < 6; i++) { cw.src[i] = Wo; cw.dst[i] = ws1; cw.n[i] = 4194304; }
  convert6<<<dim3(2048, 1), blk, 0, stream>>>(cw);

  // 8. final: out = X @ Wo^T, fp32 row-major (S,B,D); writes o0/o1 (Pb dead)
  gemm_nt<3, true><<<dim3(8, 32, 1), gblk, 0, stream>>>(ws0, ws1, out, 2048, 2048, 2048, 2048, 1.0f);
}